// Round 1
// baseline (11332.204 us; speedup 1.0000x reference)
//
#include <hip/hip_runtime.h>

// GRU: T=1024 B=64 D=256 H=512 O=256.
// Strategy:
//  - prep: cast x->bf16, build transposed bf16 weights (WhT[G][H], WiT[G][D], WoT[O][H]),
//          init h_buf[0]=bf16(h0), zero barrier words.
//  - scan: 64 persistent WGs x 384 thr. 4 independent batch groups (16 rows each),
//          16 WGs/group, private group barrier per step. Weights in registers.
//          Fused x@Wi (no xg materialization). h double-buffered in ws (bf16).
//  - ogemm: out = hs @ Wo + bo via bf16 MFMA.
// ws usage ~103.4 MB.

#define T_ 1024
#define B_ 64
#define D_ 256
#define H_ 512
#define G_ 1536
#define O_ 256

typedef __attribute__((ext_vector_type(8))) short short8;
typedef __attribute__((ext_vector_type(4))) float float4v;

static __device__ __forceinline__ unsigned short f2b(float f) {
  unsigned u = __builtin_bit_cast(unsigned, f);
  u += 0x7fffu + ((u >> 16) & 1u);          // RNE (no NaN special-case; inputs are finite)
  return (unsigned short)(u >> 16);
}

// ---------------------------------------------------------------- prep ------
__global__ __launch_bounds__(256) void prep_kernel(
    const float* __restrict__ x, const float* __restrict__ Wi,
    const float* __restrict__ Wh, const float* __restrict__ Wo,
    const float* __restrict__ h0,
    unsigned short* __restrict__ xb, unsigned short* __restrict__ WhT,
    unsigned short* __restrict__ WiT, unsigned short* __restrict__ WoT,
    unsigned short* __restrict__ hbuf, unsigned* __restrict__ bar)
{
  const size_t NXB = (size_t)T_ * B_ * D_;     // 16777216
  const size_t NWH = (size_t)G_ * H_;          // 786432
  const size_t NWI = (size_t)G_ * D_;          // 393216
  const size_t NWO = (size_t)O_ * H_;          // 131072
  const size_t NH0 = (size_t)B_ * H_;          // 32768
  const size_t NBAR = 256;                     // u32 words
  const size_t NTOT = NXB + NWH + NWI + NWO + NH0 + NBAR;
  size_t i = (size_t)blockIdx.x * blockDim.x + threadIdx.x;
  const size_t stride = (size_t)gridDim.x * blockDim.x;
  for (; i < NTOT; i += stride) {
    if (i < NXB) { xb[i] = f2b(x[i]); continue; }
    size_t j = i - NXB;
    if (j < NWH) { size_t g = j >> 9, k = j & 511; WhT[j] = f2b(Wh[k * G_ + g]); continue; }
    j -= NWH;
    if (j < NWI) { size_t g = j >> 8, k = j & 255; WiT[j] = f2b(Wi[k * G_ + g]); continue; }
    j -= NWI;
    if (j < NWO) { size_t o = j >> 9, k = j & 511; WoT[j] = f2b(Wo[k * O_ + o]); continue; }
    j -= NWO;
    if (j < NH0) { hbuf[j] = f2b(h0[j]); continue; }
    j -= NH0;
    bar[j] = 0u;
  }
}

// ---------------------------------------------------------------- scan ------
// grid 64, block 384 (6 waves). wave = s*3+gk: gk in {r,z,n}, s in {0,1} col-halves.
// WG covers batch rows [group*16,+16) and h-cols [slice*32,+32).
__global__ __launch_bounds__(384, 2) void scan_kernel(
    const unsigned short* __restrict__ xb,
    const unsigned short* __restrict__ WhT,
    const unsigned short* __restrict__ WiT,
    unsigned short* __restrict__ hbuf,
    unsigned short* __restrict__ hs,
    const float* __restrict__ bi,
    const float* __restrict__ bhn,
    const float* __restrict__ h0,
    unsigned* __restrict__ bar)
{
  const int wg = blockIdx.x;                       // 0..63
  const int group = (wg & 7) >> 1;                 // 0..3  (XCD-pair locality if %8 rr)
  const int slice = ((wg & 1) << 3) | (wg >> 3);   // 0..15
  const int tid = threadIdx.x;
  const int wave = tid >> 6;                       // 0..5
  const int lane = tid & 63;
  const int m = lane & 15;
  const int quad = lane >> 4;
  const int gk = wave % 3;                         // 0:r 1:z 2:n
  const int s = wave / 3;                          // 0,1
  const int row0 = group * 16;
  const int jbase = slice * 32 + s * 16;           // h-col base of this wave's tile
  const int gcol = gk * 512 + jbase + m;           // gate column for B operand

  __shared__ float lds_h[6][256];
  __shared__ float lds_x[6][256];

  // persistent B fragments (registers): Wh part K=512 (16 ksteps), Wi part K=256 (8)
  short8 Bh[16], Bx[8];
  {
    const unsigned short* p = WhT + (size_t)gcol * H_ + quad * 8;
#pragma unroll
    for (int k = 0; k < 16; ++k) Bh[k] = *(const short8*)(p + k * 32);
    const unsigned short* q = WiT + (size_t)gcol * D_ + quad * 8;
#pragma unroll
    for (int k = 0; k < 8; ++k) Bx[k] = *(const short8*)(q + k * 32);
  }

  // gate-phase per-lane constants (used by gk==0 waves; cheap for all)
  const int jcol = jbase + m;
  const float bi_r = bi[jcol];
  const float bi_z = bi[512 + jcol];
  const float bi_n = bi[1024 + jcol];
  const float bhn_c = bhn[jcol];
  float hold[4];
#pragma unroll
  for (int i = 0; i < 4; ++i)
    hold[i] = h0[(size_t)(row0 + quad * 4 + i) * H_ + jcol];

  unsigned* cnt = bar + group * 64;
  unsigned* gen = bar + group * 64 + 32;

  int p = 0;
  for (int t = 0; t < T_; ++t) {
    float4v acch = {0.f, 0.f, 0.f, 0.f};
    float4v accx = {0.f, 0.f, 0.f, 0.f};
    // A fragments stream from global (L2-resident): h rows of this group
    const unsigned short* hp =
        hbuf + (size_t)p * (B_ * H_) + (size_t)(row0 + m) * H_ + quad * 8;
#pragma unroll
    for (int k = 0; k < 16; ++k) {
      short8 a = *(const short8*)(hp + k * 32);
      acch = __builtin_amdgcn_mfma_f32_16x16x32_bf16(a, Bh[k], acch, 0, 0, 0);
    }
    const unsigned short* xp =
        xb + ((size_t)t * B_ + row0 + m) * D_ + quad * 8;
#pragma unroll
    for (int k = 0; k < 8; ++k) {
      short8 a = *(const short8*)(xp + k * 32);
      accx = __builtin_amdgcn_mfma_f32_16x16x32_bf16(a, Bx[k], accx, 0, 0, 0);
    }
    // exchange pre-activations (C-layout: row=quad*4+i, col=m)
#pragma unroll
    for (int i = 0; i < 4; ++i) {
      const int idx = (quad * 4 + i) * 16 + m;
      lds_h[wave][idx] = acch[i];
      lds_x[wave][idx] = accx[i];
    }
    __syncthreads();
    if (gk == 0) {
      const int wb = s * 3;
#pragma unroll
      for (int i = 0; i < 4; ++i) {
        const int r = quad * 4 + i;
        const int idx = r * 16 + m;
        const float pr = lds_h[wb + 0][idx] + lds_x[wb + 0][idx] + bi_r;
        const float pz = lds_h[wb + 1][idx] + lds_x[wb + 1][idx] + bi_z;
        const float rg = 1.f / (1.f + __expf(-pr));
        const float zg = 1.f / (1.f + __expf(-pz));
        const float ng = tanhf(lds_x[wb + 2][idx] + bi_n + rg * (lds_h[wb + 2][idx] + bhn_c));
        const float hn = (1.f - zg) * ng + zg * hold[i];
        hold[i] = hn;                              // keep fp32 copy for next update
        const unsigned short hb = f2b(hn);
        const size_t off = (size_t)(row0 + r) * H_ + jcol;
        hbuf[(size_t)(p ^ 1) * (B_ * H_) + off] = hb;
        hs[((size_t)t * B_ + row0 + r) * H_ + jcol] = hb;
      }
    }
    __syncthreads();   // drain ALL waves' h_new stores before signaling arrival
    // ---- private group barrier (16 WGs), monotonic count/generation ----
    if (tid == 0) {
      __threadfence();
      unsigned arr = __hip_atomic_fetch_add(cnt, 1u, __ATOMIC_ACQ_REL,
                                            __HIP_MEMORY_SCOPE_AGENT);
      const unsigned tgt = 16u * (unsigned)(t + 1);
      if (arr == tgt - 1u) {
        __hip_atomic_store(gen, tgt, __ATOMIC_RELEASE, __HIP_MEMORY_SCOPE_AGENT);
      } else {
        while (__hip_atomic_load(gen, __ATOMIC_ACQUIRE, __HIP_MEMORY_SCOPE_AGENT) < tgt) {
          __builtin_amdgcn_s_sleep(1);
        }
      }
      __threadfence();
    }
    __syncthreads();
    p ^= 1;
  }
}

// ---------------------------------------------------------------- ogemm -----
// out[65536 x 256] = hs[65536 x 512] @ Wo[512 x 256] + bo. WG: 64 rows x 256 cols.
__global__ __launch_bounds__(256) void ogemm_kernel(
    const unsigned short* __restrict__ hs, const unsigned short* __restrict__ WoT,
    const float* __restrict__ bo, float* __restrict__ out)
{
  const int wv = threadIdx.x >> 6, lane = threadIdx.x & 63;
  const int m = lane & 15, quad = lane >> 4;
  const int rowbase = blockIdx.x * 64 + wv * 16;
  const unsigned short* ap = hs + (size_t)(rowbase + m) * H_ + quad * 8;
  float4v acc[16];
#pragma unroll
  for (int n = 0; n < 16; ++n) { float4v z = {0.f,0.f,0.f,0.f}; acc[n] = z; }
#pragma unroll
  for (int k = 0; k < 16; ++k) {
    short8 a = *(const short8*)(ap + k * 32);
#pragma unroll
    for (int n = 0; n < 16; ++n) {
      short8 b = *(const short8*)(WoT + (size_t)(n * 16 + m) * H_ + k * 32 + quad * 8);
      acc[n] = __builtin_amdgcn_mfma_f32_16x16x32_bf16(a, b, acc[n], 0, 0, 0);
    }
  }
#pragma unroll
  for (int n = 0; n < 16; ++n) {
    const int col = n * 16 + m;
    const float bias = bo[col];
#pragma unroll
    for (int i = 0; i < 4; ++i) {
      const int r = rowbase + quad * 4 + i;
      out[(size_t)r * O_ + col] = acc[n][i] + bias;
    }
  }
}

// ---------------------------------------------------------------- launch ----
extern "C" void kernel_launch(void* const* d_in, const int* in_sizes, int n_in,
                              void* d_out, int out_size, void* d_ws, size_t ws_size,
                              hipStream_t stream)
{
  const float* x   = (const float*)d_in[0];
  const float* Wi  = (const float*)d_in[1];
  const float* bi  = (const float*)d_in[2];
  const float* Wh  = (const float*)d_in[3];
  const float* bhn = (const float*)d_in[4];
  const float* Wo  = (const float*)d_in[5];
  const float* bo  = (const float*)d_in[6];
  const float* h0  = (const float*)d_in[7];
  float* out = (float*)d_out;

  char* ws = (char*)d_ws;
  unsigned short* xb   = (unsigned short*)ws;  ws += (size_t)T_ * B_ * D_ * 2;  // 33.5 MB
  unsigned short* WhT  = (unsigned short*)ws;  ws += (size_t)G_ * H_ * 2;       // 1.5 MB
  unsigned short* WiT  = (unsigned short*)ws;  ws += (size_t)G_ * D_ * 2;       // 0.75 MB
  unsigned short* WoT  = (unsigned short*)ws;  ws += (size_t)O_ * H_ * 2;       // 0.25 MB
  unsigned short* hbuf = (unsigned short*)ws;  ws += (size_t)2 * B_ * H_ * 2;   // 128 KB
  unsigned short* hs   = (unsigned short*)ws;  ws += (size_t)T_ * B_ * H_ * 2;  // 67 MB
  unsigned* bar        = (unsigned*)ws;                                          // 1 KB

  prep_kernel<<<4096, 256, 0, stream>>>(x, Wi, Wh, Wo, h0, xb, WhT, WiT, WoT, hbuf, bar);
  scan_kernel<<<64, 384, 0, stream>>>(xb, WhT, WiT, hbuf, hs, bi, bhn, h0, bar);
  ogemm_kernel<<<1024, 256, 0, stream>>>(hs, WoT, bo, out);
}

// Round 2
// 4629.898 us; speedup vs baseline: 2.4476x; 2.4476x over previous
//
#include <hip/hip_runtime.h>

// GRU: T=1024 B=64 D=256 H=512 O=256.
// Round 2: replace centralized fetch_add barrier + threadfence (wbl2/inv) with
// fine-grained coherence: sc0sc1 write-through h stores into hs[t] (rotating
// addresses => consumer plain loads are always cold => served from IF),
// distributed per-WG flags (one coalesced 64B poll line per group), no cache
// maintenance ops at all. Cooperative LDS staging of the h tile (was 6x
// redundant), XOR-swizzled for ds_read_b128. x-GEMM loads issued before poll.

#define T_ 1024
#define B_ 64
#define D_ 256
#define H_ 512
#define G_ 1536
#define O_ 256

typedef __attribute__((ext_vector_type(8))) short short8;
typedef __attribute__((ext_vector_type(4))) float float4v;

static __device__ __forceinline__ unsigned short f2b(float f) {
  unsigned u = __builtin_bit_cast(unsigned, f);
  u += 0x7fffu + ((u >> 16) & 1u);          // RNE (finite inputs)
  return (unsigned short)(u >> 16);
}

// ---------------------------------------------------------------- prep ------
__global__ __launch_bounds__(256) void prep_kernel(
    const float* __restrict__ x, const float* __restrict__ Wi,
    const float* __restrict__ Wh, const float* __restrict__ Wo,
    unsigned short* __restrict__ xb, unsigned short* __restrict__ WhT,
    unsigned short* __restrict__ WiT, unsigned short* __restrict__ WoT,
    unsigned* __restrict__ flags)
{
  const size_t NXB = (size_t)T_ * B_ * D_;
  const size_t NWH = (size_t)G_ * H_;
  const size_t NWI = (size_t)G_ * D_;
  const size_t NWO = (size_t)O_ * H_;
  const size_t NFL = 256;
  const size_t NTOT = NXB + NWH + NWI + NWO + NFL;
  size_t i = (size_t)blockIdx.x * blockDim.x + threadIdx.x;
  const size_t stride = (size_t)gridDim.x * blockDim.x;
  for (; i < NTOT; i += stride) {
    if (i < NXB) { xb[i] = f2b(x[i]); continue; }
    size_t j = i - NXB;
    if (j < NWH) { size_t g = j >> 9, k = j & 511; WhT[j] = f2b(Wh[k * G_ + g]); continue; }
    j -= NWH;
    if (j < NWI) { size_t g = j >> 8, k = j & 255; WiT[j] = f2b(Wi[k * G_ + g]); continue; }
    j -= NWI;
    if (j < NWO) { size_t o = j >> 9, k = j & 511; WoT[j] = f2b(Wo[k * O_ + o]); continue; }
    j -= NWO;
    flags[j] = 0u;
  }
}

// ---------------------------------------------------------------- scan ------
// 64 WGs x 384 thr (6 waves). group = wg&3 (16 rows), slice = wg>>2 (32 h-cols).
// wave = (gk = wave%3, s = wave/3); wave's gate-cols = gk*512 + slice*32 + s*16.
__global__ __launch_bounds__(384, 2) void scan_kernel(
    const unsigned short* __restrict__ xb,
    const unsigned short* __restrict__ WhT,
    const unsigned short* __restrict__ WiT,
    unsigned short* __restrict__ hs,
    const float* __restrict__ bi,
    const float* __restrict__ bhn,
    const float* __restrict__ h0,
    unsigned* __restrict__ flags)
{
  const int wg = blockIdx.x;
  const int group = wg & 3;
  const int slice = wg >> 2;
  const int tid = threadIdx.x;
  const int wave = tid >> 6;
  const int lane = tid & 63;
  const int m = lane & 15;
  const int quad = lane >> 4;
  const int gk = wave % 3;
  const int s = wave / 3;
  const int row0 = group * 16;
  const int jbase = slice * 32 + s * 16;
  const int gcol = gk * 512 + jbase + m;

  __shared__ unsigned short hT[16 * 512];     // h tile, XOR-swizzled 16B blocks
  __shared__ float lds_h[6][256];
  __shared__ float lds_x[6][256];

  // persistent B fragments
  short8 Bh[16], Bx[8];
  {
    const unsigned short* p = WhT + (size_t)gcol * H_ + quad * 8;
#pragma unroll
    for (int k = 0; k < 16; ++k) Bh[k] = *(const short8*)(p + k * 32);
    const unsigned short* q = WiT + (size_t)gcol * D_ + quad * 8;
#pragma unroll
    for (int k = 0; k < 8; ++k) Bx[k] = *(const short8*)(q + k * 32);
  }

  const int jcol = jbase + m;
  const float bi_r = bi[jcol];
  const float bi_z = bi[512 + jcol];
  const float bi_n = bi[1024 + jcol];
  const float bhn_c = bhn[jcol];
  float hold[4];
#pragma unroll
  for (int i = 0; i < 4; ++i)
    hold[i] = h0[(size_t)(row0 + quad * 4 + i) * H_ + jcol];

  // preamble: h0 -> hT (bf16, swizzled)
  for (int i = tid; i < 16 * 512; i += 384) {
    int r = i >> 9, c = i & 511;
    int c2 = (((c >> 3) ^ (r & 7)) << 3) | (c & 7);
    hT[r * 512 + c2] = f2b(h0[(size_t)(row0 + r) * H_ + c]);
  }
  // accx for t=0
  float4v accx = {0.f, 0.f, 0.f, 0.f};
  {
    const unsigned short* xp = xb + ((size_t)0 * B_ + row0 + m) * D_ + quad * 8;
#pragma unroll
    for (int k = 0; k < 8; ++k)
      accx = __builtin_amdgcn_mfma_f32_16x16x32_bf16(*(const short8*)(xp + k * 32), Bx[k], accx, 0, 0, 0);
  }
  __syncthreads();

  unsigned* const myflag = flags + group * 16 + slice;
  const unsigned* const gflags = flags + group * 16;

  for (int t = 0; t < T_; ++t) {
    // h-part MFMAs from LDS tile
    float4v acch = {0.f, 0.f, 0.f, 0.f};
#pragma unroll
    for (int k = 0; k < 16; ++k) {
      const int blk = (k * 4 + quad) ^ (m & 7);
      short8 a = *(const short8*)&hT[m * 512 + blk * 8];
      acch = __builtin_amdgcn_mfma_f32_16x16x32_bf16(a, Bh[k], acch, 0, 0, 0);
    }
    // exchange pre-activations
#pragma unroll
    for (int i = 0; i < 4; ++i) {
      const int idx = (quad * 4 + i) * 16 + m;
      lds_h[wave][idx] = acch[i];
      lds_x[wave][idx] = accx[i];
    }
    __syncthreads();
    if (gk == 0) {
      const int wb = s * 3;
#pragma unroll
      for (int i = 0; i < 4; ++i) {
        const int r = quad * 4 + i;
        const int idx = r * 16 + m;
        const float pr = lds_h[wb + 0][idx] + lds_x[wb + 0][idx] + bi_r;
        const float pz = lds_h[wb + 1][idx] + lds_x[wb + 1][idx] + bi_z;
        const float rg = 1.f / (1.f + __expf(-pr));
        const float zg = 1.f / (1.f + __expf(-pz));
        const float ng = tanhf(lds_x[wb + 2][idx] + bi_n + rg * (lds_h[wb + 2][idx] + bhn_c));
        const float hn = (1.f - zg) * ng + zg * hold[i];
        hold[i] = hn;
        const unsigned hb = (unsigned)f2b(hn);
        const unsigned short* p = hs + (((size_t)t * B_ + row0 + r) * H_ + jcol);
        asm volatile("global_store_short %0, %1, off sc0 sc1"
                     :: "v"(p), "v"(hb) : "memory");
      }
      asm volatile("s_waitcnt vmcnt(0)" ::: "memory");  // h at coherence point
    }
    __syncthreads();   // all producer waves drained before flag
    if (tid == 0)
      __hip_atomic_store(myflag, (unsigned)(t + 1), __ATOMIC_RELAXED,
                         __HIP_MEMORY_SCOPE_AGENT);
    if (t < T_ - 1) {
      // issue x loads for t+1 (in flight during poll)
      short8 xa[8];
      const unsigned short* xp = xb + ((size_t)(t + 1) * B_ + row0 + m) * D_ + quad * 8;
#pragma unroll
      for (int k = 0; k < 8; ++k) xa[k] = *(const short8*)(xp + k * 32);
      // poll all 16 producer flags of this group (one coalesced 64B line)
      if (lane < 16) {
        while (__hip_atomic_load(gflags + lane, __ATOMIC_RELAXED,
                                 __HIP_MEMORY_SCOPE_AGENT) < (unsigned)(t + 1))
          __builtin_amdgcn_s_sleep(1);
      }
      asm volatile("" ::: "memory");   // compiler fence only (no cache ops)
      // cooperative load hs[t] (16 rows x 512, contiguous 16KB) -> hT swizzled
      const unsigned short* src = hs + ((size_t)t * B_ + row0) * H_;
#pragma unroll 3
      for (int c = tid; c < 1024; c += 384) {
        const int r = c >> 6;
        const int b2 = (c & 63) ^ (r & 7);
        *(short8*)&hT[r * 512 + b2 * 8] = *(const short8*)(src + (size_t)c * 8);
      }
      // x MFMAs for t+1
      float4v ax = {0.f, 0.f, 0.f, 0.f};
#pragma unroll
      for (int k = 0; k < 8; ++k)
        ax = __builtin_amdgcn_mfma_f32_16x16x32_bf16(xa[k], Bx[k], ax, 0, 0, 0);
      accx = ax;
      __syncthreads();
    }
  }
}

// ---------------------------------------------------------------- ogemm -----
__global__ __launch_bounds__(256) void ogemm_kernel(
    const unsigned short* __restrict__ hs, const unsigned short* __restrict__ WoT,
    const float* __restrict__ bo, float* __restrict__ out)
{
  const int wv = threadIdx.x >> 6, lane = threadIdx.x & 63;
  const int m = lane & 15, quad = lane >> 4;
  const int rowbase = blockIdx.x * 64 + wv * 16;
  const unsigned short* ap = hs + (size_t)(rowbase + m) * H_ + quad * 8;
  float4v acc[16];
#pragma unroll
  for (int n = 0; n < 16; ++n) { float4v z = {0.f,0.f,0.f,0.f}; acc[n] = z; }
#pragma unroll
  for (int k = 0; k < 16; ++k) {
    short8 a = *(const short8*)(ap + k * 32);
#pragma unroll
    for (int n = 0; n < 16; ++n) {
      short8 b = *(const short8*)(WoT + (size_t)(n * 16 + m) * H_ + k * 32 + quad * 8);
      acc[n] = __builtin_amdgcn_mfma_f32_16x16x32_bf16(a, b, acc[n], 0, 0, 0);
    }
  }
#pragma unroll
  for (int n = 0; n < 16; ++n) {
    const int col = n * 16 + m;
    const float bias = bo[col];
#pragma unroll
    for (int i = 0; i < 4; ++i) {
      const int r = rowbase + quad * 4 + i;
      out[(size_t)r * O_ + col] = acc[n][i] + bias;
    }
  }
}

// ---------------------------------------------------------------- launch ----
extern "C" void kernel_launch(void* const* d_in, const int* in_sizes, int n_in,
                              void* d_out, int out_size, void* d_ws, size_t ws_size,
                              hipStream_t stream)
{
  const float* x   = (const float*)d_in[0];
  const float* Wi  = (const float*)d_in[1];
  const float* bi  = (const float*)d_in[2];
  const float* Wh  = (const float*)d_in[3];
  const float* bhn = (const float*)d_in[4];
  const float* Wo  = (const float*)d_in[5];
  const float* bo  = (const float*)d_in[6];
  const float* h0  = (const float*)d_in[7];
  float* out = (float*)d_out;

  char* ws = (char*)d_ws;
  unsigned short* xb  = (unsigned short*)ws;  ws += (size_t)T_ * B_ * D_ * 2;  // 33.5 MB
  unsigned short* WhT = (unsigned short*)ws;  ws += (size_t)G_ * H_ * 2;       // 1.5 MB
  unsigned short* WiT = (unsigned short*)ws;  ws += (size_t)G_ * D_ * 2;       // 0.75 MB
  unsigned short* WoT = (unsigned short*)ws;  ws += (size_t)O_ * H_ * 2;       // 0.25 MB
  unsigned short* hs  = (unsigned short*)ws;  ws += (size_t)T_ * B_ * H_ * 2;  // 67 MB
  unsigned* flags     = (unsigned*)ws;                                          // 1 KB

  prep_kernel<<<4096, 256, 0, stream>>>(x, Wi, Wh, Wo, xb, WhT, WiT, WoT, flags);
  scan_kernel<<<64, 384, 0, stream>>>(xb, WhT, WiT, hs, bi, bhn, h0, flags);
  ogemm_kernel<<<1024, 256, 0, stream>>>(hs, WoT, bo, out);
}